// Round 10
// baseline (322.201 us; speedup 1.0000x reference)
//
#include <hip/hip_runtime.h>
#include <hip/hip_bf16.h>

// LIVE subproblem: the reference graph is two disconnected halves and the
// output reads only h[n1:], so x1 / edge-chunk-1 are dead. We compute on the
// 20000-node second half with edges = ei2 ∪ ei1 (local indices).
#define NN  20000           // live nodes
#define EC  160000
#define ETN 320000          // 2*EC live edges
#define CINC 128
#define HC 4
#define NBLK 79             // ceil(NN/256)

typedef __attribute__((ext_vector_type(8))) short short8v;
typedef __attribute__((ext_vector_type(4))) float f32x4;

__device__ __forceinline__ ushort f2bu(float f){
  __hip_bfloat16 h = __float2bfloat16(f);
  union { __hip_bfloat16 b; ushort u; } v; v.b = h; return v.u;
}
__device__ __forceinline__ float blo(unsigned v){ return __uint_as_float(v << 16); }
__device__ __forceinline__ float bhi(unsigned v){ return __uint_as_float(v & 0xffff0000u); }

// live edge e: e<EC -> ei2 edge; else ei1 edge (local node ids)
__device__ __forceinline__ void edge_sd(int e, const int* __restrict__ ei1,
                                        const int* __restrict__ ei2, int& s, int& d){
  if (e < EC){ s = ei2[e];      d = ei2[EC + e]; }
  else       { int t = e - EC; s = ei1[t]; d = ei1[EC + t]; }
}

__device__ __forceinline__ float4 leaky4(float4 v){
  v.x = v.x > 0.f ? v.x : 0.2f*v.x;
  v.y = v.y > 0.f ? v.y : 0.2f*v.y;
  v.z = v.z > 0.f ? v.z : 0.2f*v.z;
  v.w = v.w > 0.f ? v.w : 0.2f*v.w;
  return v;
}

// ---------- merged prep: cast x2 -> bf16, transpose+permute all 5 weights ----------
// Wt[m][k] = W[k][perm(m)], perm(m) = (m&3)*Ch + (m>>2) (Ch>0) else m
__global__ void prep_k(const float* __restrict__ x2,
                       const float* __restrict__ W0, const float* __restrict__ W1,
                       const float* __restrict__ W2, const float* __restrict__ Wf,
                       const float* __restrict__ Wres,
                       ushort* __restrict__ X0,
                       ushort* __restrict__ W0t, ushort* __restrict__ W1t,
                       ushort* __restrict__ W2t, ushort* __restrict__ Wft,
                       ushort* __restrict__ Wrt){
  int i = blockIdx.x*256 + threadIdx.x;
  if (i < NN*CINC){ X0[i] = f2bu(x2[i]); return; }
  int j = i - NN*CINC;
  const float* W; ushort* Wt; int K, M, Ch;
  if      (j <  32768){ W=W0;  Wt=W0t; K=128; M=256; Ch=64;            }
  else if (j <  49152){ W=W1;  Wt=W1t; K=64;  M=256; Ch=64;  j-=32768; }
  else if (j <  81920){ W=W2;  Wt=W2t; K=64;  M=512; Ch=128; j-=49152; }
  else if (j < 147456){ W=Wf;  Wt=Wft; K=128; M=512; Ch=128; j-=81920; }
  else if (j < 163840){ W=Wres;Wt=Wrt; K=128; M=128; Ch=0;   j-=147456;}
  else return;
  int m = j / K, k = j - m*K;
  int col = Ch ? ((m & 3)*Ch + (m >> 2)) : m;
  Wt[j] = f2bu(W[k*M + col]);
}

// ---------- MFMA GEMM + fused attention scores ----------
// H[n][m] = sum_k X[n][k]*Wt[m][k]; 64 rows/block (wave w: rows n0+16w..+16),
// block loops all M/64 column tiles; att partials accumulated in registers.
template<int K, int M, bool ATT, bool F32OUT>
__global__ __launch_bounds__(256)
void gemm_att(const ushort* __restrict__ X, const ushort* __restrict__ Wt,
              ushort* __restrict__ Hout, float* __restrict__ HoutF,
              const float* __restrict__ att_s, const float* __restrict__ att_d,
              float* __restrict__ AS, float* __restrict__ AD, int nrows){
  constexpr int C = M/4;
  __shared__ float st[4][16][68];
  const int lane = threadIdx.x & 63;
  const int w    = threadIdx.x >> 6;
  const int nb   = blockIdx.x*64 + w*16;
  const int hi = lane >> 4;      // 0..3
  const int lo = lane & 15;      // 0..15
  int ra = nb + lo; if (ra >= nrows) ra = nrows - 1;   // clamp (load safety)
  const ushort* ap = X + (long)ra*K + hi*8;
  const int row = lane >> 2, cg = lane & 3;
  const int head = lo & 3;

  float pas[4] = {0.f,0.f,0.f,0.f};
  float pad[4] = {0.f,0.f,0.f,0.f};

  #pragma unroll
  for (int mt = 0; mt < M/64; ++mt){
    const int m0 = mt*64;
    f32x4 acc[4];
    #pragma unroll
    for (int t = 0; t < 4; ++t) acc[t] = (f32x4){0.f,0.f,0.f,0.f};
    #pragma unroll
    for (int k0 = 0; k0 < K; k0 += 32){
      short8v a = *(const short8v*)(ap + k0);
      #pragma unroll
      for (int t = 0; t < 4; ++t){
        short8v b = *(const short8v*)(Wt + (long)(m0 + t*16 + lo)*K + k0 + hi*8);
        acc[t] = __builtin_amdgcn_mfma_f32_16x16x32_bf16(a, b, acc[t], 0, 0, 0);
      }
    }
    if (ATT){
      #pragma unroll
      for (int t = 0; t < 4; ++t){
        int c = (m0 + t*16 + lo) >> 2;
        float vs = att_s[head*C + c];
        float vd = att_d[head*C + c];
        #pragma unroll
        for (int j = 0; j < 4; ++j){
          pas[j] += acc[t][j]*vs;
          pad[j] += acc[t][j]*vd;
        }
      }
    }
    // epilogue through per-wave LDS
    #pragma unroll
    for (int t = 0; t < 4; ++t)
      #pragma unroll
      for (int j = 0; j < 4; ++j)
        st[w][hi*4 + j][t*16 + lo] = acc[t][j];
    __builtin_amdgcn_wave_barrier();
    if (nb + row < nrows){
      if (F32OUT){
        float* op = HoutF + (long)(nb + row)*M + m0 + cg*16;
        #pragma unroll
        for (int q = 0; q < 4; ++q)
          *(float4*)(op + q*4) = *(float4*)&st[w][row][cg*16 + q*4];
      } else {
        ushort* op = Hout + (long)(nb + row)*M + m0 + cg*16;
        #pragma unroll
        for (int q = 0; q < 4; ++q){
          float4 v = *(float4*)&st[w][row][cg*16 + q*4];
          ushort4 u; u.x = f2bu(v.x); u.y = f2bu(v.y); u.z = f2bu(v.z); u.w = f2bu(v.w);
          *(ushort4*)(op + q*4) = u;
        }
      }
    }
    __builtin_amdgcn_wave_barrier();
  }

  if (ATT){
    // reduce channel-group partials: lanes lo, lo^4, lo^8 (bits 2,3 of lane)
    #pragma unroll
    for (int j = 0; j < 4; ++j){
      pas[j] += __shfl_xor(pas[j], 4);  pas[j] += __shfl_xor(pas[j], 8);
      pad[j] += __shfl_xor(pad[j], 4);  pad[j] += __shfl_xor(pad[j], 8);
    }
    if (lo < 4){
      #pragma unroll
      for (int j = 0; j < 4; ++j){
        int r = nb + hi*4 + j;
        if (r < nrows){ AS[r*4 + lo] = pas[j]; AD[r*4 + lo] = pad[j]; }
      }
    }
  }
}

// ---------- CSR build ----------

__global__ void count_k(const int* __restrict__ ei1, const int* __restrict__ ei2,
                        int* __restrict__ CNT){
  int e = blockIdx.x*256 + threadIdx.x;
  if (e >= ETN) return;
  int s, d; edge_sd(e, ei1, ei2, s, d);
  atomicAdd(&CNT[d], 1);
}

__global__ __launch_bounds__(256) void scan_blk_k(const int* __restrict__ CNT,
                                                  int* __restrict__ EXC,
                                                  int* __restrict__ BSUM){
  __shared__ int s[256];
  const int t = threadIdx.x, b = blockIdx.x;
  const int i = b*256 + t;
  int v = (i < NN) ? CNT[i] : 0;
  s[t] = v;
  __syncthreads();
  #pragma unroll
  for (int off = 1; off < 256; off <<= 1){
    int u = (t >= off) ? s[t - off] : 0;
    __syncthreads();
    s[t] += u;
    __syncthreads();
  }
  if (i < NN) EXC[i] = s[t] - v;
  if (t == 255) BSUM[b] = s[255];
}

__global__ __launch_bounds__(256) void scan_top_k(const int* __restrict__ BSUM,
                                                  int* __restrict__ BOFF){
  __shared__ int s[256];
  const int t = threadIdx.x;
  int v = (t < NBLK) ? BSUM[t] : 0;
  s[t] = v;
  __syncthreads();
  #pragma unroll
  for (int off = 1; off < 256; off <<= 1){
    int u = (t >= off) ? s[t - off] : 0;
    __syncthreads();
    s[t] += u;
    __syncthreads();
  }
  if (t < NBLK) BOFF[t] = s[t] - v;
}

__global__ __launch_bounds__(256) void scan_add_k(const int* __restrict__ EXC,
                                                  const int* __restrict__ BOFF,
                                                  int* __restrict__ OFF,
                                                  int* __restrict__ CUR){
  int i = blockIdx.x*256 + threadIdx.x;
  if (i < NN){ int o = EXC[i] + BOFF[i >> 8]; OFF[i] = o; CUR[i] = o; }
  if (i == NN) OFF[NN] = ETN;
}

__global__ void scatter_k(const int* __restrict__ ei1, const int* __restrict__ ei2,
                          int* __restrict__ CUR, int* __restrict__ ESRC){
  int e = blockIdx.x*256 + threadIdx.x;
  if (e >= ETN) return;
  int s, d; edge_sd(e, ei1, ei2, s, d);
  int pos = atomicAdd(&CUR[d], 1);
  ESRC[pos] = s;
}

// ---------- fused per-dst softmax + aggregation, SINGLE PASS (no max-shift) ----------
// exp(x)/sum(exp(x)) == exp(x-m)/sum(exp(x-m)); scores O(15), overflow needs >88.
// H16 bf16 [n][c][h]; one wave per dst; lane covers 2 channels via one uint4 load.
template<bool RELU>
__global__ __launch_bounds__(256)
void agg128_k(const int* __restrict__ OFF, const int* __restrict__ ESRC,
              const float* __restrict__ AS, const float* __restrict__ AD,
              const ushort* __restrict__ H16, const float* __restrict__ bias,
              ushort* __restrict__ Xout){
  __shared__ int    sm_s[4][64];
  __shared__ float4 sm_p[4][64];
  const int lane = threadIdx.x & 63;
  const int w    = threadIdx.x >> 6;
  const int d    = blockIdx.x*4 + w;      // NN divisible by 4
  const int beg = OFF[d], end = OFF[d+1];
  const float4 ad4 = ((const float4*)AD)[d];

  float4 den = make_float4(0.f,0.f,0.f,0.f);
  float4 a0A = den, a1A = den, a0B = den, a1B = den;

  for (int i0 = beg; i0 < end; i0 += 64){
    int cnt = min(64, end - i0);
    if (lane < cnt){
      int s = ESRC[i0 + lane];
      float4 a = ((const float4*)AS)[s];
      float4 sc = leaky4(make_float4(a.x+ad4.x, a.y+ad4.y, a.z+ad4.z, a.w+ad4.w));
      float4 p = make_float4(__expf(sc.x), __expf(sc.y), __expf(sc.z), __expf(sc.w));
      den.x += p.x; den.y += p.y; den.z += p.z; den.w += p.w;
      sm_s[w][lane] = s;
      sm_p[w][lane] = p;
    }
    __builtin_amdgcn_wave_barrier();
    int e = 0;
    for (; e + 3 < cnt; e += 4){
      int s0 = sm_s[w][e],   s1 = sm_s[w][e+1];
      int s2 = sm_s[w][e+2], s3 = sm_s[w][e+3];
      float4 p0 = sm_p[w][e],   p1 = sm_p[w][e+1];
      float4 p2 = sm_p[w][e+2], p3 = sm_p[w][e+3];
      uint4 u0 = *(const uint4*)(H16 + (long)s0*512 + lane*8);
      uint4 u1 = *(const uint4*)(H16 + (long)s1*512 + lane*8);
      uint4 u2 = *(const uint4*)(H16 + (long)s2*512 + lane*8);
      uint4 u3 = *(const uint4*)(H16 + (long)s3*512 + lane*8);
      a0A.x += p0.x*blo(u0.x); a0A.y += p0.y*bhi(u0.x);
      a0A.z += p0.z*blo(u0.y); a0A.w += p0.w*bhi(u0.y);
      a1A.x += p0.x*blo(u0.z); a1A.y += p0.y*bhi(u0.z);
      a1A.z += p0.z*blo(u0.w); a1A.w += p0.w*bhi(u0.w);
      a0B.x += p1.x*blo(u1.x); a0B.y += p1.y*bhi(u1.x);
      a0B.z += p1.z*blo(u1.y); a0B.w += p1.w*bhi(u1.y);
      a1B.x += p1.x*blo(u1.z); a1B.y += p1.y*bhi(u1.z);
      a1B.z += p1.z*blo(u1.w); a1B.w += p1.w*bhi(u1.w);
      a0A.x += p2.x*blo(u2.x); a0A.y += p2.y*bhi(u2.x);
      a0A.z += p2.z*blo(u2.y); a0A.w += p2.w*bhi(u2.y);
      a1A.x += p2.x*blo(u2.z); a1A.y += p2.y*bhi(u2.z);
      a1A.z += p2.z*blo(u2.w); a1A.w += p2.w*bhi(u2.w);
      a0B.x += p3.x*blo(u3.x); a0B.y += p3.y*bhi(u3.x);
      a0B.z += p3.z*blo(u3.y); a0B.w += p3.w*bhi(u3.y);
      a1B.x += p3.x*blo(u3.z); a1B.y += p3.y*bhi(u3.z);
      a1B.z += p3.z*blo(u3.w); a1B.w += p3.w*bhi(u3.w);
    }
    for (; e < cnt; ++e){
      int s0 = sm_s[w][e];
      float4 p0 = sm_p[w][e];
      uint4 u0 = *(const uint4*)(H16 + (long)s0*512 + lane*8);
      a0A.x += p0.x*blo(u0.x); a0A.y += p0.y*bhi(u0.x);
      a0A.z += p0.z*blo(u0.y); a0A.w += p0.w*bhi(u0.y);
      a1A.x += p0.x*blo(u0.z); a1A.y += p0.y*bhi(u0.z);
      a1A.z += p0.z*blo(u0.w); a1A.w += p0.w*bhi(u0.w);
    }
    __builtin_amdgcn_wave_barrier();
  }

  #pragma unroll
  for (int off = 32; off; off >>= 1){
    den.x += __shfl_xor(den.x, off);
    den.y += __shfl_xor(den.y, off);
    den.z += __shfl_xor(den.z, off);
    den.w += __shfl_xor(den.w, off);
  }
  float4 r = make_float4(1.f/(den.x + 1e-16f), 1.f/(den.y + 1e-16f),
                         1.f/(den.z + 1e-16f), 1.f/(den.w + 1e-16f));
  int c0 = lane*2;
  float o0 = 0.25f*((a0A.x+a0B.x)*r.x + (a0A.y+a0B.y)*r.y +
                    (a0A.z+a0B.z)*r.z + (a0A.w+a0B.w)*r.w) + bias[c0];
  float o1 = 0.25f*((a1A.x+a1B.x)*r.x + (a1A.y+a1B.y)*r.y +
                    (a1A.z+a1B.z)*r.z + (a1A.w+a1B.w)*r.w) + bias[c0+1];
  if (RELU){ o0 = fmaxf(o0, 0.f); o1 = fmaxf(o1, 0.f); }
  ((unsigned*)Xout)[(long)d*64 + lane] = (unsigned)f2bu(o0) | ((unsigned)f2bu(o1) << 16);
}

// layer-f variant: no relu, fused row-norm + residual + bres, f32 output.
__global__ __launch_bounds__(256)
void agg128_final_k(const int* __restrict__ OFF, const int* __restrict__ ESRC,
                    const float* __restrict__ AS, const float* __restrict__ AD,
                    const ushort* __restrict__ H16, const float* __restrict__ bias,
                    const float* __restrict__ RES, const float* __restrict__ bres,
                    float* __restrict__ out){
  __shared__ int    sm_s[4][64];
  __shared__ float4 sm_p[4][64];
  const int lane = threadIdx.x & 63;
  const int w    = threadIdx.x >> 6;
  const int d    = blockIdx.x*4 + w;
  const int beg = OFF[d], end = OFF[d+1];
  const float4 ad4 = ((const float4*)AD)[d];

  float4 den = make_float4(0.f,0.f,0.f,0.f);
  float4 a0A = den, a1A = den, a0B = den, a1B = den;

  for (int i0 = beg; i0 < end; i0 += 64){
    int cnt = min(64, end - i0);
    if (lane < cnt){
      int s = ESRC[i0 + lane];
      float4 a = ((const float4*)AS)[s];
      float4 sc = leaky4(make_float4(a.x+ad4.x, a.y+ad4.y, a.z+ad4.z, a.w+ad4.w));
      float4 p = make_float4(__expf(sc.x), __expf(sc.y), __expf(sc.z), __expf(sc.w));
      den.x += p.x; den.y += p.y; den.z += p.z; den.w += p.w;
      sm_s[w][lane] = s;
      sm_p[w][lane] = p;
    }
    __builtin_amdgcn_wave_barrier();
    int e = 0;
    for (; e + 3 < cnt; e += 4){
      int s0 = sm_s[w][e],   s1 = sm_s[w][e+1];
      int s2 = sm_s[w][e+2], s3 = sm_s[w][e+3];
      float4 p0 = sm_p[w][e],   p1 = sm_p[w][e+1];
      float4 p2 = sm_p[w][e+2], p3 = sm_p[w][e+3];
      uint4 u0 = *(const uint4*)(H16 + (long)s0*512 + lane*8);
      uint4 u1 = *(const uint4*)(H16 + (long)s1*512 + lane*8);
      uint4 u2 = *(const uint4*)(H16 + (long)s2*512 + lane*8);
      uint4 u3 = *(const uint4*)(H16 + (long)s3*512 + lane*8);
      a0A.x += p0.x*blo(u0.x); a0A.y += p0.y*bhi(u0.x);
      a0A.z += p0.z*blo(u0.y); a0A.w += p0.w*bhi(u0.y);
      a1A.x += p0.x*blo(u0.z); a1A.y += p0.y*bhi(u0.z);
      a1A.z += p0.z*blo(u0.w); a1A.w += p0.w*bhi(u0.w);
      a0B.x += p1.x*blo(u1.x); a0B.y += p1.y*bhi(u1.x);
      a0B.z += p1.z*blo(u1.y); a0B.w += p1.w*bhi(u1.y);
      a1B.x += p1.x*blo(u1.z); a1B.y += p1.y*bhi(u1.z);
      a1B.z += p1.z*blo(u1.w); a1B.w += p1.w*bhi(u1.w);
      a0A.x += p2.x*blo(u2.x); a0A.y += p2.y*bhi(u2.x);
      a0A.z += p2.z*blo(u2.y); a0A.w += p2.w*bhi(u2.y);
      a1A.x += p2.x*blo(u2.z); a1A.y += p2.y*bhi(u2.z);
      a1A.z += p2.z*blo(u2.w); a1A.w += p2.w*bhi(u2.w);
      a0B.x += p3.x*blo(u3.x); a0B.y += p3.y*bhi(u3.x);
      a0B.z += p3.z*blo(u3.y); a0B.w += p3.w*bhi(u3.y);
      a1B.x += p3.x*blo(u3.z); a1B.y += p3.y*bhi(u3.z);
      a1B.z += p3.z*blo(u3.w); a1B.w += p3.w*bhi(u3.w);
    }
    for (; e < cnt; ++e){
      int s0 = sm_s[w][e];
      float4 p0 = sm_p[w][e];
      uint4 u0 = *(const uint4*)(H16 + (long)s0*512 + lane*8);
      a0A.x += p0.x*blo(u0.x); a0A.y += p0.y*bhi(u0.x);
      a0A.z += p0.z*blo(u0.y); a0A.w += p0.w*bhi(u0.y);
      a1A.x += p0.x*blo(u0.z); a1A.y += p0.y*bhi(u0.z);
      a1A.z += p0.z*blo(u0.w); a1A.w += p0.w*bhi(u0.w);
    }
    __builtin_amdgcn_wave_barrier();
  }

  #pragma unroll
  for (int off = 32; off; off >>= 1){
    den.x += __shfl_xor(den.x, off);
    den.y += __shfl_xor(den.y, off);
    den.z += __shfl_xor(den.z, off);
    den.w += __shfl_xor(den.w, off);
  }
  float4 r = make_float4(1.f/(den.x + 1e-16f), 1.f/(den.y + 1e-16f),
                         1.f/(den.z + 1e-16f), 1.f/(den.w + 1e-16f));
  int c0 = lane*2;
  float o0 = 0.25f*((a0A.x+a0B.x)*r.x + (a0A.y+a0B.y)*r.y +
                    (a0A.z+a0B.z)*r.z + (a0A.w+a0B.w)*r.w) + bias[c0];
  float o1 = 0.25f*((a1A.x+a1B.x)*r.x + (a1A.y+a1B.y)*r.y +
                    (a1A.z+a1B.z)*r.z + (a1A.w+a1B.w)*r.w) + bias[c0+1];

  // fused: L2-normalize row, add residual + bres
  float ss = o0*o0 + o1*o1;
  #pragma unroll
  for (int off = 32; off; off >>= 1) ss += __shfl_xor(ss, off);
  float inv = 1.f / fmaxf(sqrtf(ss), 1e-12f);
  float2 res = *(const float2*)(RES + (long)d*CINC + c0);
  float2 ov;
  ov.x = o0*inv + res.x + bres[c0];
  ov.y = o1*inv + res.y + bres[c0+1];
  *(float2*)(out + (long)d*CINC + c0) = ov;
}

// C=64: lanes split in halves; each iteration processes 2 edges (one per half).
template<bool RELU>
__global__ __launch_bounds__(256)
void agg64_k(const int* __restrict__ OFF, const int* __restrict__ ESRC,
             const float* __restrict__ AS, const float* __restrict__ AD,
             const ushort* __restrict__ H16, const float* __restrict__ bias,
             ushort* __restrict__ Xout){
  __shared__ int    sm_s[4][64];
  __shared__ float4 sm_p[4][64];
  const int lane = threadIdx.x & 63;
  const int half = lane >> 5;             // 0 or 1
  const int l5   = lane & 31;             // channel pair index
  const int w    = threadIdx.x >> 6;
  const int d    = blockIdx.x*4 + w;
  const int beg = OFF[d], end = OFF[d+1];
  const float4 ad4 = ((const float4*)AD)[d];

  float4 den = make_float4(0.f,0.f,0.f,0.f);
  float4 a0 = den, a1 = den;              // 2 channels × 4 heads

  for (int i0 = beg; i0 < end; i0 += 64){
    int cnt = min(64, end - i0);
    if (lane < cnt){
      int s = ESRC[i0 + lane];
      float4 a = ((const float4*)AS)[s];
      float4 sc = leaky4(make_float4(a.x+ad4.x, a.y+ad4.y, a.z+ad4.z, a.w+ad4.w));
      float4 p = make_float4(__expf(sc.x), __expf(sc.y), __expf(sc.z), __expf(sc.w));
      den.x += p.x; den.y += p.y; den.z += p.z; den.w += p.w;
      sm_s[w][lane] = s;
      sm_p[w][lane] = p;
    }
    __builtin_amdgcn_wave_barrier();
    int e = 0;
    #pragma unroll 4
    for (; e + 1 < cnt; e += 2){
      int ee = e + half;
      int s0 = sm_s[w][ee];
      float4 p0 = sm_p[w][ee];
      uint4 u0 = *(const uint4*)(H16 + (long)s0*256 + l5*8);
      a0.x += p0.x*blo(u0.x); a0.y += p0.y*bhi(u0.x);
      a0.z += p0.z*blo(u0.y); a0.w += p0.w*bhi(u0.y);
      a1.x += p0.x*blo(u0.z); a1.y += p0.y*bhi(u0.z);
      a1.z += p0.z*blo(u0.w); a1.w += p0.w*bhi(u0.w);
    }
    if (e < cnt && half == 0){
      int s0 = sm_s[w][e];
      float4 p0 = sm_p[w][e];
      uint4 u0 = *(const uint4*)(H16 + (long)s0*256 + l5*8);
      a0.x += p0.x*blo(u0.x); a0.y += p0.y*bhi(u0.x);
      a0.z += p0.z*blo(u0.y); a0.w += p0.w*bhi(u0.y);
      a1.x += p0.x*blo(u0.z); a1.y += p0.y*bhi(u0.z);
      a1.z += p0.z*blo(u0.w); a1.w += p0.w*bhi(u0.w);
    }
    __builtin_amdgcn_wave_barrier();
  }

  #pragma unroll
  for (int off = 32; off; off >>= 1){
    den.x += __shfl_xor(den.x, off);
    den.y += __shfl_xor(den.y, off);
    den.z += __shfl_xor(den.z, off);
    den.w += __shfl_xor(den.w, off);
  }
  a0.x += __shfl_xor(a0.x, 32); a0.y += __shfl_xor(a0.y, 32);
  a0.z += __shfl_xor(a0.z, 32); a0.w += __shfl_xor(a0.w, 32);
  a1.x += __shfl_xor(a1.x, 32); a1.y += __shfl_xor(a1.y, 32);
  a1.z += __shfl_xor(a1.z, 32); a1.w += __shfl_xor(a1.w, 32);

  if (half == 0){
    float4 r = make_float4(1.f/(den.x + 1e-16f), 1.f/(den.y + 1e-16f),
                           1.f/(den.z + 1e-16f), 1.f/(den.w + 1e-16f));
    int c0 = l5*2;
    float o0 = 0.25f*(a0.x*r.x + a0.y*r.y + a0.z*r.z + a0.w*r.w) + bias[c0];
    float o1 = 0.25f*(a1.x*r.x + a1.y*r.y + a1.z*r.z + a1.w*r.w) + bias[c0+1];
    if (RELU){ o0 = fmaxf(o0, 0.f); o1 = fmaxf(o1, 0.f); }
    ((unsigned*)Xout)[(long)d*32 + l5] = (unsigned)f2bu(o0) | ((unsigned)f2bu(o1) << 16);
  }
}

// ---------- launch ----------

extern "C" void kernel_launch(void* const* d_in, const int* in_sizes, int n_in,
                              void* d_out, int out_size, void* d_ws, size_t ws_size,
                              hipStream_t stream) {
  const float* x2  = (const float*)d_in[1];
  const int*   ei1 = (const int*)  d_in[2];
  const int*   ei2 = (const int*)  d_in[3];
  const float* W0  = (const float*)d_in[4];
  const float* a0s = (const float*)d_in[5];
  const float* a0d = (const float*)d_in[6];
  const float* b0  = (const float*)d_in[7];
  const float* W1  = (const float*)d_in[8];
  const float* a1s = (const float*)d_in[9];
  const float* a1d = (const float*)d_in[10];
  const float* b1  = (const float*)d_in[11];
  const float* W2  = (const float*)d_in[12];
  const float* a2s = (const float*)d_in[13];
  const float* a2d = (const float*)d_in[14];
  const float* b2  = (const float*)d_in[15];
  const float* Wf  = (const float*)d_in[16];
  const float* afs = (const float*)d_in[17];
  const float* afd = (const float*)d_in[18];
  const float* bf  = (const float*)d_in[19];
  const float* Wres= (const float*)d_in[20];
  const float* bres= (const float*)d_in[21];
  float* out = (float*)d_out;

  char* ws = (char*)d_ws;
  ushort* X0   = (ushort*)(ws + 0);            // 5,120,000 B
  ushort* X1   = (ushort*)(ws + 5120000);      // 5,120,000 B
  ushort* H16  = (ushort*)(ws + 10240000);     // 20,480,000 B
  float*  RES  = (float*) (ws + 30720000);     // 10,240,000 B
  float*  AS   = (float*) (ws + 40960000);     // 320,000 B
  float*  AD   = (float*) (ws + 41280000);     // 320,000 B
  int*    OFF  = (int*)   (ws + 41600000);     // 80,064 B
  int*    CUR  = (int*)   (ws + 41680064);     // 80,000 B
  int*    ESRC = (int*)   (ws + 41760064);     // 1,280,000 B
  int*    CNT  = (int*)   (ws + 43040064);     // 80,000 B
  ushort* W0t  = (ushort*)(ws + 43120064);     // 65,536 B
  ushort* W1t  = (ushort*)(ws + 43185600);     // 32,768 B
  ushort* W2t  = (ushort*)(ws + 43218368);     // 65,536 B
  ushort* Wft  = (ushort*)(ws + 43283904);     // 131,072 B
  ushort* Wrt  = (ushort*)(ws + 43414976);     // 32,768 B
  int*    EXC  = (int*)   (ws + 43447744);     // 80,000 B
  int*    BSUM = (int*)   (ws + 43527744);     // 1,024 B
  int*    BOFF = (int*)   (ws + 43528768);     // 1,024 B

  const int EG = (ETN + 255)/256;   // 1250
  const int GB = (NN + 63)/64;      // 313 blocks for fused gemm

  // prep: cast x2 + all weight transposes in one dispatch
  prep_k<<<(NN*CINC + 163840 + 255)/256, 256, 0, stream>>>(
      x2, W0, W1, W2, Wf, Wres, X0, W0t, W1t, W2t, Wft, Wrt);

  // CSR build
  hipMemsetAsync(CNT, 0, NN*4, stream);
  count_k<<<EG, 256, 0, stream>>>(ei1, ei2, CNT);
  scan_blk_k<<<NBLK, 256, 0, stream>>>(CNT, EXC, BSUM);
  scan_top_k<<<1, 256, 0, stream>>>(BSUM, BOFF);
  scan_add_k<<<NBLK, 256, 0, stream>>>(EXC, BOFF, OFF, CUR);
  scatter_k<<<EG, 256, 0, stream>>>(ei1, ei2, CUR, ESRC);

  // residual = x2 @ Wres (f32 out; consumed by fused final)
  gemm_att<128,128,false,true><<<GB, 256, 0, stream>>>(
      X0, Wrt, nullptr, RES, nullptr, nullptr, nullptr, nullptr, NN);

  // ---- layer 0: K=128, C=64, relu ----
  gemm_att<128,256,true,false><<<GB, 256, 0, stream>>>(
      X0, W0t, H16, nullptr, a0s, a0d, AS, AD, NN);
  agg64_k<true><<<NN/4, 256, 0, stream>>>(OFF, ESRC, AS, AD, H16, b0, X1);

  // ---- layer 1: K=64, C=64, relu ----
  gemm_att<64,256,true,false><<<GB, 256, 0, stream>>>(
      X1, W1t, H16, nullptr, a1s, a1d, AS, AD, NN);
  agg64_k<true><<<NN/4, 256, 0, stream>>>(OFF, ESRC, AS, AD, H16, b1, X0);

  // ---- layer 2: K=64, C=128, relu ----
  gemm_att<64,512,true,false><<<GB, 256, 0, stream>>>(
      X0, W2t, H16, nullptr, a2s, a2d, AS, AD, NN);
  agg128_k<true><<<NN/4, 256, 0, stream>>>(OFF, ESRC, AS, AD, H16, b2, X1);

  // ---- layer f: K=128, C=128, fused norm+residual output ----
  gemm_att<128,512,true,false><<<GB, 256, 0, stream>>>(
      X1, Wft, H16, nullptr, afs, afd, AS, AD, NN);
  agg128_final_k<<<NN/4, 256, 0, stream>>>(OFF, ESRC, AS, AD, H16, bf, RES, bres, out);
}

// Round 11
// 301.974 us; speedup vs baseline: 1.0670x; 1.0670x over previous
//
#include <hip/hip_runtime.h>
#include <hip/hip_bf16.h>

// LIVE subproblem: the reference graph is two disconnected halves and the
// output reads only h[n1:], so x1 / edge-chunk-1 are dead. We compute on the
// 20000-node second half with edges = ei2 ∪ ei1 (local indices).
#define NN  20000           // live nodes
#define EC  160000
#define ETN 320000          // 2*EC live edges
#define CINC 128
#define HC 4
#define NBLK 79             // ceil(NN/256)

typedef __attribute__((ext_vector_type(8))) short short8v;
typedef __attribute__((ext_vector_type(4))) float f32x4;

__device__ __forceinline__ ushort f2bu(float f){
  __hip_bfloat16 h = __float2bfloat16(f);
  union { __hip_bfloat16 b; ushort u; } v; v.b = h; return v.u;
}
__device__ __forceinline__ float blo(unsigned v){ return __uint_as_float(v << 16); }
__device__ __forceinline__ float bhi(unsigned v){ return __uint_as_float(v & 0xffff0000u); }

// live edge e: e<EC -> ei2 edge; else ei1 edge (local node ids)
__device__ __forceinline__ void edge_sd(int e, const int* __restrict__ ei1,
                                        const int* __restrict__ ei2, int& s, int& d){
  if (e < EC){ s = ei2[e];      d = ei2[EC + e]; }
  else       { int t = e - EC; s = ei1[t]; d = ei1[EC + t]; }
}

__device__ __forceinline__ float4 leaky4(float4 v){
  v.x = v.x > 0.f ? v.x : 0.2f*v.x;
  v.y = v.y > 0.f ? v.y : 0.2f*v.y;
  v.z = v.z > 0.f ? v.z : 0.2f*v.z;
  v.w = v.w > 0.f ? v.w : 0.2f*v.w;
  return v;
}

// ---------- merged prep: cast x2 -> bf16, transpose+permute all 5 weights ----------
// Wt[m][k] = W[k][perm(m)], perm(m) = (m&3)*Ch + (m>>2) (Ch>0) else m
__global__ void prep_k(const float* __restrict__ x2,
                       const float* __restrict__ W0, const float* __restrict__ W1,
                       const float* __restrict__ W2, const float* __restrict__ Wf,
                       const float* __restrict__ Wres,
                       ushort* __restrict__ X0,
                       ushort* __restrict__ W0t, ushort* __restrict__ W1t,
                       ushort* __restrict__ W2t, ushort* __restrict__ Wft,
                       ushort* __restrict__ Wrt){
  int i = blockIdx.x*256 + threadIdx.x;
  if (i < NN*CINC){ X0[i] = f2bu(x2[i]); return; }
  int j = i - NN*CINC;
  const float* W; ushort* Wt; int K, M, Ch;
  if      (j <  32768){ W=W0;  Wt=W0t; K=128; M=256; Ch=64;            }
  else if (j <  49152){ W=W1;  Wt=W1t; K=64;  M=256; Ch=64;  j-=32768; }
  else if (j <  81920){ W=W2;  Wt=W2t; K=64;  M=512; Ch=128; j-=49152; }
  else if (j < 147456){ W=Wf;  Wt=Wft; K=128; M=512; Ch=128; j-=81920; }
  else if (j < 163840){ W=Wres;Wt=Wrt; K=128; M=128; Ch=0;   j-=147456;}
  else return;
  int m = j / K, k = j - m*K;
  int col = Ch ? ((m & 3)*Ch + (m >> 2)) : m;
  Wt[j] = f2bu(W[k*M + col]);
}

// ---------- MFMA GEMM: H[n][m] = sum_k X[n][k] * Wt[m][k] ----------
// 128 rows per block (2 row-tiles per wave); each B-frag feeds 2 MFMAs.
// Grid: (ceil(n/128), M/64) — column-parallel, high occupancy.
template<int K, bool F32OUT>
__global__ __launch_bounds__(256)
void gemm_mfma(const ushort* __restrict__ X, const ushort* __restrict__ Wt,
               ushort* __restrict__ Hout, float* __restrict__ HoutF, int nrows, int M){
  __shared__ float st[4][16][68];
  const int lane = threadIdx.x & 63;
  const int w    = threadIdx.x >> 6;
  const int n0   = blockIdx.x*128 + w*16;       // tile0 rows; tile1 = +64
  const int m0   = blockIdx.y*64;
  const int hi = lane >> 4;      // 0..3
  const int lo = lane & 15;      // 0..15
  int ra0 = n0 + lo;      if (ra0 >= nrows) ra0 = nrows - 1;
  int ra1 = n0 + 64 + lo; if (ra1 >= nrows) ra1 = nrows - 1;
  const ushort* ap0 = X + (long)ra0*K + hi*8;
  const ushort* ap1 = X + (long)ra1*K + hi*8;

  f32x4 acc0[4], acc1[4];
  #pragma unroll
  for (int t = 0; t < 4; ++t){ acc0[t] = (f32x4){0.f,0.f,0.f,0.f}; acc1[t] = acc0[t]; }

  #pragma unroll
  for (int k0 = 0; k0 < K; k0 += 32){
    short8v a0 = *(const short8v*)(ap0 + k0);
    short8v a1 = *(const short8v*)(ap1 + k0);
    #pragma unroll
    for (int t = 0; t < 4; ++t){
      short8v b = *(const short8v*)(Wt + (long)(m0 + t*16 + lo)*K + k0 + hi*8);
      acc0[t] = __builtin_amdgcn_mfma_f32_16x16x32_bf16(a0, b, acc0[t], 0, 0, 0);
      acc1[t] = __builtin_amdgcn_mfma_f32_16x16x32_bf16(a1, b, acc1[t], 0, 0, 0);
    }
  }

  const int row = lane >> 2, cg = lane & 3;
  #pragma unroll
  for (int half = 0; half < 2; ++half){
    f32x4* acc = half ? acc1 : acc0;
    const int nb = n0 + half*64;
    #pragma unroll
    for (int t = 0; t < 4; ++t)
      #pragma unroll
      for (int j = 0; j < 4; ++j)
        st[w][hi*4 + j][t*16 + lo] = acc[t][j];
    __builtin_amdgcn_wave_barrier();
    if (nb + row < nrows){
      if (F32OUT){
        float* op = HoutF + (long)(nb + row)*M + m0 + cg*16;
        #pragma unroll
        for (int q = 0; q < 4; ++q)
          *(float4*)(op + q*4) = *(float4*)&st[w][row][cg*16 + q*4];
      } else {
        ushort* op = Hout + (long)(nb + row)*M + m0 + cg*16;
        #pragma unroll
        for (int q = 0; q < 4; ++q){
          float4 v = *(float4*)&st[w][row][cg*16 + q*4];
          ushort4 u; u.x = f2bu(v.x); u.y = f2bu(v.y); u.z = f2bu(v.z); u.w = f2bu(v.w);
          *(ushort4*)(op + q*4) = u;
        }
      }
    }
    __builtin_amdgcn_wave_barrier();
  }
}

// ---------- attention scores: wave per node, lane = channel ----------
template<int C>
__global__ __launch_bounds__(256)
void att_scores_w(const ushort* __restrict__ H16, const float* __restrict__ att_s,
                  const float* __restrict__ att_d, float* __restrict__ AS,
                  float* __restrict__ AD){
  const int lane = threadIdx.x & 63;
  const int w    = threadIdx.x >> 6;
  const int n    = blockIdx.x*4 + w;          // NN divisible by 4
  const ushort* hp = H16 + (long)n*(HC*C);
  float as0=0.f, as1=0.f, as2=0.f, as3=0.f;
  float ad0=0.f, ad1=0.f, ad2=0.f, ad3=0.f;
  #pragma unroll
  for (int j = 0; j < C/64; ++j){
    int c = lane + j*64;
    uint2 u = *(const uint2*)(hp + c*4);
    float h0 = blo(u.x);
    float h1 = bhi(u.x);
    float h2 = blo(u.y);
    float h3 = bhi(u.y);
    as0 += h0*att_s[0*C + c]; ad0 += h0*att_d[0*C + c];
    as1 += h1*att_s[1*C + c]; ad1 += h1*att_d[1*C + c];
    as2 += h2*att_s[2*C + c]; ad2 += h2*att_d[2*C + c];
    as3 += h3*att_s[3*C + c]; ad3 += h3*att_d[3*C + c];
  }
  #pragma unroll
  for (int off = 32; off; off >>= 1){
    as0 += __shfl_xor(as0, off); ad0 += __shfl_xor(ad0, off);
    as1 += __shfl_xor(as1, off); ad1 += __shfl_xor(ad1, off);
    as2 += __shfl_xor(as2, off); ad2 += __shfl_xor(ad2, off);
    as3 += __shfl_xor(as3, off); ad3 += __shfl_xor(ad3, off);
  }
  if (lane == 0){
    ((float4*)AS)[n] = make_float4(as0, as1, as2, as3);
    ((float4*)AD)[n] = make_float4(ad0, ad1, ad2, ad3);
  }
}

// ---------- CSR build ----------

__global__ void count_k(const int* __restrict__ ei1, const int* __restrict__ ei2,
                        int* __restrict__ CNT){
  int e = blockIdx.x*256 + threadIdx.x;
  if (e >= ETN) return;
  int s, d; edge_sd(e, ei1, ei2, s, d);
  atomicAdd(&CNT[d], 1);
}

__global__ __launch_bounds__(256) void scan_blk_k(const int* __restrict__ CNT,
                                                  int* __restrict__ EXC,
                                                  int* __restrict__ BSUM){
  __shared__ int s[256];
  const int t = threadIdx.x, b = blockIdx.x;
  const int i = b*256 + t;
  int v = (i < NN) ? CNT[i] : 0;
  s[t] = v;
  __syncthreads();
  #pragma unroll
  for (int off = 1; off < 256; off <<= 1){
    int u = (t >= off) ? s[t - off] : 0;
    __syncthreads();
    s[t] += u;
    __syncthreads();
  }
  if (i < NN) EXC[i] = s[t] - v;
  if (t == 255) BSUM[b] = s[255];
}

__global__ __launch_bounds__(256) void scan_top_k(const int* __restrict__ BSUM,
                                                  int* __restrict__ BOFF){
  __shared__ int s[256];
  const int t = threadIdx.x;
  int v = (t < NBLK) ? BSUM[t] : 0;
  s[t] = v;
  __syncthreads();
  #pragma unroll
  for (int off = 1; off < 256; off <<= 1){
    int u = (t >= off) ? s[t - off] : 0;
    __syncthreads();
    s[t] += u;
    __syncthreads();
  }
  if (t < NBLK) BOFF[t] = s[t] - v;
}

__global__ __launch_bounds__(256) void scan_add_k(const int* __restrict__ EXC,
                                                  const int* __restrict__ BOFF,
                                                  int* __restrict__ OFF,
                                                  int* __restrict__ CUR){
  int i = blockIdx.x*256 + threadIdx.x;
  if (i < NN){ int o = EXC[i] + BOFF[i >> 8]; OFF[i] = o; CUR[i] = o; }
  if (i == NN) OFF[NN] = ETN;
}

__global__ void scatter_k(const int* __restrict__ ei1, const int* __restrict__ ei2,
                          int* __restrict__ CUR, int* __restrict__ ESRC){
  int e = blockIdx.x*256 + threadIdx.x;
  if (e >= ETN) return;
  int s, d; edge_sd(e, ei1, ei2, s, d);
  int pos = atomicAdd(&CUR[d], 1);
  ESRC[pos] = s;
}

// ---------- fused per-dst softmax + aggregation, SINGLE PASS (no max-shift) ----------
// exp(x)/sum(exp(x)) == exp(x-m)/sum(exp(x-m)); scores O(15), overflow needs >88.
// H16 bf16 [n][c][h]; one wave per dst; lane covers 2 channels via one uint4 load.
template<bool RELU>
__global__ __launch_bounds__(256)
void agg128_k(const int* __restrict__ OFF, const int* __restrict__ ESRC,
              const float* __restrict__ AS, const float* __restrict__ AD,
              const ushort* __restrict__ H16, const float* __restrict__ bias,
              ushort* __restrict__ Xout){
  __shared__ int    sm_s[4][64];
  __shared__ float4 sm_p[4][64];
  const int lane = threadIdx.x & 63;
  const int w    = threadIdx.x >> 6;
  const int d    = blockIdx.x*4 + w;      // NN divisible by 4
  const int beg = OFF[d], end = OFF[d+1];
  const float4 ad4 = ((const float4*)AD)[d];

  float4 den = make_float4(0.f,0.f,0.f,0.f);
  float4 a0A = den, a1A = den, a0B = den, a1B = den;

  for (int i0 = beg; i0 < end; i0 += 64){
    int cnt = min(64, end - i0);
    if (lane < cnt){
      int s = ESRC[i0 + lane];
      float4 a = ((const float4*)AS)[s];
      float4 sc = leaky4(make_float4(a.x+ad4.x, a.y+ad4.y, a.z+ad4.z, a.w+ad4.w));
      float4 p = make_float4(__expf(sc.x), __expf(sc.y), __expf(sc.z), __expf(sc.w));
      den.x += p.x; den.y += p.y; den.z += p.z; den.w += p.w;
      sm_s[w][lane] = s;
      sm_p[w][lane] = p;
    }
    __builtin_amdgcn_wave_barrier();
    int e = 0;
    for (; e + 3 < cnt; e += 4){
      int s0 = sm_s[w][e],   s1 = sm_s[w][e+1];
      int s2 = sm_s[w][e+2], s3 = sm_s[w][e+3];
      float4 p0 = sm_p[w][e],   p1 = sm_p[w][e+1];
      float4 p2 = sm_p[w][e+2], p3 = sm_p[w][e+3];
      uint4 u0 = *(const uint4*)(H16 + (long)s0*512 + lane*8);
      uint4 u1 = *(const uint4*)(H16 + (long)s1*512 + lane*8);
      uint4 u2 = *(const uint4*)(H16 + (long)s2*512 + lane*8);
      uint4 u3 = *(const uint4*)(H16 + (long)s3*512 + lane*8);
      a0A.x += p0.x*blo(u0.x); a0A.y += p0.y*bhi(u0.x);
      a0A.z += p0.z*blo(u0.y); a0A.w += p0.w*bhi(u0.y);
      a1A.x += p0.x*blo(u0.z); a1A.y += p0.y*bhi(u0.z);
      a1A.z += p0.z*blo(u0.w); a1A.w += p0.w*bhi(u0.w);
      a0B.x += p1.x*blo(u1.x); a0B.y += p1.y*bhi(u1.x);
      a0B.z += p1.z*blo(u1.y); a0B.w += p1.w*bhi(u1.y);
      a1B.x += p1.x*blo(u1.z); a1B.y += p1.y*bhi(u1.z);
      a1B.z += p1.z*blo(u1.w); a1B.w += p1.w*bhi(u1.w);
      a0A.x += p2.x*blo(u2.x); a0A.y += p2.y*bhi(u2.x);
      a0A.z += p2.z*blo(u2.y); a0A.w += p2.w*bhi(u2.y);
      a1A.x += p2.x*blo(u2.z); a1A.y += p2.y*bhi(u2.z);
      a1A.z += p2.z*blo(u2.w); a1A.w += p2.w*bhi(u2.w);
      a0B.x += p3.x*blo(u3.x); a0B.y += p3.y*bhi(u3.x);
      a0B.z += p3.z*blo(u3.y); a0B.w += p3.w*bhi(u3.y);
      a1B.x += p3.x*blo(u3.z); a1B.y += p3.y*bhi(u3.z);
      a1B.z += p3.z*blo(u3.w); a1B.w += p3.w*bhi(u3.w);
    }
    for (; e < cnt; ++e){
      int s0 = sm_s[w][e];
      float4 p0 = sm_p[w][e];
      uint4 u0 = *(const uint4*)(H16 + (long)s0*512 + lane*8);
      a0A.x += p0.x*blo(u0.x); a0A.y += p0.y*bhi(u0.x);
      a0A.z += p0.z*blo(u0.y); a0A.w += p0.w*bhi(u0.y);
      a1A.x += p0.x*blo(u0.z); a1A.y += p0.y*bhi(u0.z);
      a1A.z += p0.z*blo(u0.w); a1A.w += p0.w*bhi(u0.w);
    }
    __builtin_amdgcn_wave_barrier();
  }

  #pragma unroll
  for (int off = 32; off; off >>= 1){
    den.x += __shfl_xor(den.x, off);
    den.y += __shfl_xor(den.y, off);
    den.z += __shfl_xor(den.z, off);
    den.w += __shfl_xor(den.w, off);
  }
  float4 r = make_float4(1.f/(den.x + 1e-16f), 1.f/(den.y + 1e-16f),
                         1.f/(den.z + 1e-16f), 1.f/(den.w + 1e-16f));
  int c0 = lane*2;
  float o0 = 0.25f*((a0A.x+a0B.x)*r.x + (a0A.y+a0B.y)*r.y +
                    (a0A.z+a0B.z)*r.z + (a0A.w+a0B.w)*r.w) + bias[c0];
  float o1 = 0.25f*((a1A.x+a1B.x)*r.x + (a1A.y+a1B.y)*r.y +
                    (a1A.z+a1B.z)*r.z + (a1A.w+a1B.w)*r.w) + bias[c0+1];
  if (RELU){ o0 = fmaxf(o0, 0.f); o1 = fmaxf(o1, 0.f); }
  ((unsigned*)Xout)[(long)d*64 + lane] = (unsigned)f2bu(o0) | ((unsigned)f2bu(o1) << 16);
}

// layer-f variant: no relu, fused row-norm + residual + bres, f32 output.
__global__ __launch_bounds__(256)
void agg128_final_k(const int* __restrict__ OFF, const int* __restrict__ ESRC,
                    const float* __restrict__ AS, const float* __restrict__ AD,
                    const ushort* __restrict__ H16, const float* __restrict__ bias,
                    const float* __restrict__ RES, const float* __restrict__ bres,
                    float* __restrict__ out){
  __shared__ int    sm_s[4][64];
  __shared__ float4 sm_p[4][64];
  const int lane = threadIdx.x & 63;
  const int w    = threadIdx.x >> 6;
  const int d    = blockIdx.x*4 + w;
  const int beg = OFF[d], end = OFF[d+1];
  const float4 ad4 = ((const float4*)AD)[d];

  float4 den = make_float4(0.f,0.f,0.f,0.f);
  float4 a0A = den, a1A = den, a0B = den, a1B = den;

  for (int i0 = beg; i0 < end; i0 += 64){
    int cnt = min(64, end - i0);
    if (lane < cnt){
      int s = ESRC[i0 + lane];
      float4 a = ((const float4*)AS)[s];
      float4 sc = leaky4(make_float4(a.x+ad4.x, a.y+ad4.y, a.z+ad4.z, a.w+ad4.w));
      float4 p = make_float4(__expf(sc.x), __expf(sc.y), __expf(sc.z), __expf(sc.w));
      den.x += p.x; den.y += p.y; den.z += p.z; den.w += p.w;
      sm_s[w][lane] = s;
      sm_p[w][lane] = p;
    }
    __builtin_amdgcn_wave_barrier();
    int e = 0;
    for (; e + 3 < cnt; e += 4){
      int s0 = sm_s[w][e],   s1 = sm_s[w][e+1];
      int s2 = sm_s[w][e+2], s3 = sm_s[w][e+3];
      float4 p0 = sm_p[w][e],   p1 = sm_p[w][e+1];
      float4 p2 = sm_p[w][e+2], p3 = sm_p[w][e+3];
      uint4 u0 = *(const uint4*)(H16 + (long)s0*512 + lane*8);
      uint4 u1 = *(const uint4*)(H16 + (long)s1*512 + lane*8);
      uint4 u2 = *(const uint4*)(H16 + (long)s2*512 + lane*8);
      uint4 u3 = *(const uint4*)(H16 + (long)s3*512 + lane*8);
      a0A.x += p0.x*blo(u0.x); a0A.y += p0.y*bhi(u0.x);
      a0A.z += p0.z*blo(u0.y); a0A.w += p0.w*bhi(u0.y);
      a1A.x += p0.x*blo(u0.z); a1A.y += p0.y*bhi(u0.z);
      a1A.z += p0.z*blo(u0.w); a1A.w += p0.w*bhi(u0.w);
      a0B.x += p1.x*blo(u1.x); a0B.y += p1.y*bhi(u1.x);
      a0B.z += p1.z*blo(u1.y); a0B.w += p1.w*bhi(u1.y);
      a1B.x += p1.x*blo(u1.z); a1B.y += p1.y*bhi(u1.z);
      a1B.z += p1.z*blo(u1.w); a1B.w += p1.w*bhi(u1.w);
      a0A.x += p2.x*blo(u2.x); a0A.y += p2.y*bhi(u2.x);
      a0A.z += p2.z*blo(u2.y); a0A.w += p2.w*bhi(u2.y);
      a1A.x += p2.x*blo(u2.z); a1A.y += p2.y*bhi(u2.z);
      a1A.z += p2.z*blo(u2.w); a1A.w += p2.w*bhi(u2.w);
      a0B.x += p3.x*blo(u3.x); a0B.y += p3.y*bhi(u3.x);
      a0B.z += p3.z*blo(u3.y); a0B.w += p3.w*bhi(u3.y);
      a1B.x += p3.x*blo(u3.z); a1B.y += p3.y*bhi(u3.z);
      a1B.z += p3.z*blo(u3.w); a1B.w += p3.w*bhi(u3.w);
    }
    for (; e < cnt; ++e){
      int s0 = sm_s[w][e];
      float4 p0 = sm_p[w][e];
      uint4 u0 = *(const uint4*)(H16 + (long)s0*512 + lane*8);
      a0A.x += p0.x*blo(u0.x); a0A.y += p0.y*bhi(u0.x);
      a0A.z += p0.z*blo(u0.y); a0A.w += p0.w*bhi(u0.y);
      a1A.x += p0.x*blo(u0.z); a1A.y += p0.y*bhi(u0.z);
      a1A.z += p0.z*blo(u0.w); a1A.w += p0.w*bhi(u0.w);
    }
    __builtin_amdgcn_wave_barrier();
  }

  #pragma unroll
  for (int off = 32; off; off >>= 1){
    den.x += __shfl_xor(den.x, off);
    den.y += __shfl_xor(den.y, off);
    den.z += __shfl_xor(den.z, off);
    den.w += __shfl_xor(den.w, off);
  }
  float4 r = make_float4(1.f/(den.x + 1e-16f), 1.f/(den.y + 1e-16f),
                         1.f/(den.z + 1e-16f), 1.f/(den.w + 1e-16f));
  int c0 = lane*2;
  float o0 = 0.25f*((a0A.x+a0B.x)*r.x + (a0A.y+a0B.y)*r.y +
                    (a0A.z+a0B.z)*r.z + (a0A.w+a0B.w)*r.w) + bias[c0];
  float o1 = 0.25f*((a1A.x+a1B.x)*r.x + (a1A.y+a1B.y)*r.y +
                    (a1A.z+a1B.z)*r.z + (a1A.w+a1B.w)*r.w) + bias[c0+1];

  // fused: L2-normalize row, add residual + bres
  float ss = o0*o0 + o1*o1;
  #pragma unroll
  for (int off = 32; off; off >>= 1) ss += __shfl_xor(ss, off);
  float inv = 1.f / fmaxf(sqrtf(ss), 1e-12f);
  float2 res = *(const float2*)(RES + (long)d*CINC + c0);
  float2 ov;
  ov.x = o0*inv + res.x + bres[c0];
  ov.y = o1*inv + res.y + bres[c0+1];
  *(float2*)(out + (long)d*CINC + c0) = ov;
}

// C=64: lanes split in halves; each iteration processes 2 edges (one per half).
template<bool RELU>
__global__ __launch_bounds__(256)
void agg64_k(const int* __restrict__ OFF, const int* __restrict__ ESRC,
             const float* __restrict__ AS, const float* __restrict__ AD,
             const ushort* __restrict__ H16, const float* __restrict__ bias,
             ushort* __restrict__ Xout){
  __shared__ int    sm_s[4][64];
  __shared__ float4 sm_p[4][64];
  const int lane = threadIdx.x & 63;
  const int half = lane >> 5;             // 0 or 1
  const int l5   = lane & 31;             // channel pair index
  const int w    = threadIdx.x >> 6;
  const int d    = blockIdx.x*4 + w;
  const int beg = OFF[d], end = OFF[d+1];
  const float4 ad4 = ((const float4*)AD)[d];

  float4 den = make_float4(0.f,0.f,0.f,0.f);
  float4 a0 = den, a1 = den;              // 2 channels × 4 heads

  for (int i0 = beg; i0 < end; i0 += 64){
    int cnt = min(64, end - i0);
    if (lane < cnt){
      int s = ESRC[i0 + lane];
      float4 a = ((const float4*)AS)[s];
      float4 sc = leaky4(make_float4(a.x+ad4.x, a.y+ad4.y, a.z+ad4.z, a.w+ad4.w));
      float4 p = make_float4(__expf(sc.x), __expf(sc.y), __expf(sc.z), __expf(sc.w));
      den.x += p.x; den.y += p.y; den.z += p.z; den.w += p.w;
      sm_s[w][lane] = s;
      sm_p[w][lane] = p;
    }
    __builtin_amdgcn_wave_barrier();
    int e = 0;
    #pragma unroll 4
    for (; e + 1 < cnt; e += 2){
      int ee = e + half;
      int s0 = sm_s[w][ee];
      float4 p0 = sm_p[w][ee];
      uint4 u0 = *(const uint4*)(H16 + (long)s0*256 + l5*8);
      a0.x += p0.x*blo(u0.x); a0.y += p0.y*bhi(u0.x);
      a0.z += p0.z*blo(u0.y); a0.w += p0.w*bhi(u0.y);
      a1.x += p0.x*blo(u0.z); a1.y += p0.y*bhi(u0.z);
      a1.z += p0.z*blo(u0.w); a1.w += p0.w*bhi(u0.w);
    }
    if (e < cnt && half == 0){
      int s0 = sm_s[w][e];
      float4 p0 = sm_p[w][e];
      uint4 u0 = *(const uint4*)(H16 + (long)s0*256 + l5*8);
      a0.x += p0.x*blo(u0.x); a0.y += p0.y*bhi(u0.x);
      a0.z += p0.z*blo(u0.y); a0.w += p0.w*bhi(u0.y);
      a1.x += p0.x*blo(u0.z); a1.y += p0.y*bhi(u0.z);
      a1.z += p0.z*blo(u0.w); a1.w += p0.w*bhi(u0.w);
    }
    __builtin_amdgcn_wave_barrier();
  }

  #pragma unroll
  for (int off = 32; off; off >>= 1){
    den.x += __shfl_xor(den.x, off);
    den.y += __shfl_xor(den.y, off);
    den.z += __shfl_xor(den.z, off);
    den.w += __shfl_xor(den.w, off);
  }
  a0.x += __shfl_xor(a0.x, 32); a0.y += __shfl_xor(a0.y, 32);
  a0.z += __shfl_xor(a0.z, 32); a0.w += __shfl_xor(a0.w, 32);
  a1.x += __shfl_xor(a1.x, 32); a1.y += __shfl_xor(a1.y, 32);
  a1.z += __shfl_xor(a1.z, 32); a1.w += __shfl_xor(a1.w, 32);

  if (half == 0){
    float4 r = make_float4(1.f/(den.x + 1e-16f), 1.f/(den.y + 1e-16f),
                           1.f/(den.z + 1e-16f), 1.f/(den.w + 1e-16f));
    int c0 = l5*2;
    float o0 = 0.25f*(a0.x*r.x + a0.y*r.y + a0.z*r.z + a0.w*r.w) + bias[c0];
    float o1 = 0.25f*(a1.x*r.x + a1.y*r.y + a1.z*r.z + a1.w*r.w) + bias[c0+1];
    if (RELU){ o0 = fmaxf(o0, 0.f); o1 = fmaxf(o1, 0.f); }
    ((unsigned*)Xout)[(long)d*32 + l5] = (unsigned)f2bu(o0) | ((unsigned)f2bu(o1) << 16);
  }
}

// ---------- launch ----------

extern "C" void kernel_launch(void* const* d_in, const int* in_sizes, int n_in,
                              void* d_out, int out_size, void* d_ws, size_t ws_size,
                              hipStream_t stream) {
  const float* x2  = (const float*)d_in[1];
  const int*   ei1 = (const int*)  d_in[2];
  const int*   ei2 = (const int*)  d_in[3];
  const float* W0  = (const float*)d_in[4];
  const float* a0s = (const float*)d_in[5];
  const float* a0d = (const float*)d_in[6];
  const float* b0  = (const float*)d_in[7];
  const float* W1  = (const float*)d_in[8];
  const float* a1s = (const float*)d_in[9];
  const float* a1d = (const float*)d_in[10];
  const float* b1  = (const float*)d_in[11];
  const float* W2  = (const float*)d_in[12];
  const float* a2s = (const float*)d_in[13];
  const float* a2d = (const float*)d_in[14];
  const float* b2  = (const float*)d_in[15];
  const float* Wf  = (const float*)d_in[16];
  const float* afs = (const float*)d_in[17];
  const float* afd = (const float*)d_in[18];
  const float* bf  = (const float*)d_in[19];
  const float* Wres= (const float*)d_in[20];
  const float* bres= (const float*)d_in[21];
  float* out = (float*)d_out;

  char* ws = (char*)d_ws;
  ushort* X0   = (ushort*)(ws + 0);            // 5,120,000 B
  ushort* X1   = (ushort*)(ws + 5120000);      // 5,120,000 B
  ushort* H16  = (ushort*)(ws + 10240000);     // 20,480,000 B
  float*  RES  = (float*) (ws + 30720000);     // 10,240,000 B
  float*  AS   = (float*) (ws + 40960000);     // 320,000 B
  float*  AD   = (float*) (ws + 41280000);     // 320,000 B
  int*    OFF  = (int*)   (ws + 41600000);     // 80,064 B
  int*    CUR  = (int*)   (ws + 41680064);     // 80,000 B
  int*    ESRC = (int*)   (ws + 41760064);     // 1,280,000 B
  int*    CNT  = (int*)   (ws + 43040064);     // 80,000 B
  ushort* W0t  = (ushort*)(ws + 43120064);     // 65,536 B
  ushort* W1t  = (ushort*)(ws + 43185600);     // 32,768 B
  ushort* W2t  = (ushort*)(ws + 43218368);     // 65,536 B
  ushort* Wft  = (ushort*)(ws + 43283904);     // 131,072 B
  ushort* Wrt  = (ushort*)(ws + 43414976);     // 32,768 B
  int*    EXC  = (int*)   (ws + 43447744);     // 80,000 B
  int*    BSUM = (int*)   (ws + 43527744);     // 1,024 B
  int*    BOFF = (int*)   (ws + 43528768);     // 1,024 B

  const int EG = (ETN + 255)/256;   // 1250

  // prep: cast x2 + all weight transposes in one dispatch
  prep_k<<<(NN*CINC + 163840 + 255)/256, 256, 0, stream>>>(
      x2, W0, W1, W2, Wf, Wres, X0, W0t, W1t, W2t, Wft, Wrt);

  // CSR build
  hipMemsetAsync(CNT, 0, NN*4, stream);
  count_k<<<EG, 256, 0, stream>>>(ei1, ei2, CNT);
  scan_blk_k<<<NBLK, 256, 0, stream>>>(CNT, EXC, BSUM);
  scan_top_k<<<1, 256, 0, stream>>>(BSUM, BOFF);
  scan_add_k<<<NBLK, 256, 0, stream>>>(EXC, BOFF, OFF, CUR);
  scatter_k<<<EG, 256, 0, stream>>>(ei1, ei2, CUR, ESRC);

  // residual = x2 @ Wres (f32 out; consumed by fused final)
  {
    dim3 g((NN + 127)/128, 128/64);
    gemm_mfma<128,true><<<g, 256, 0, stream>>>(X0, Wrt, nullptr, RES, NN, 128);
  }

  // ---- layer 0: K=128, C=64, relu ----
  { dim3 g((NN + 127)/128, 256/64);
    gemm_mfma<128,false><<<g, 256, 0, stream>>>(X0, W0t, H16, nullptr, NN, 256); }
  att_scores_w<64><<<NN/4, 256, 0, stream>>>(H16, a0s, a0d, AS, AD);
  agg64_k<true><<<NN/4, 256, 0, stream>>>(OFF, ESRC, AS, AD, H16, b0, X1);

  // ---- layer 1: K=64, C=64, relu ----
  { dim3 g((NN + 127)/128, 256/64);
    gemm_mfma<64,false><<<g, 256, 0, stream>>>(X1, W1t, H16, nullptr, NN, 256); }
  att_scores_w<64><<<NN/4, 256, 0, stream>>>(H16, a1s, a1d, AS, AD);
  agg64_k<true><<<NN/4, 256, 0, stream>>>(OFF, ESRC, AS, AD, H16, b1, X0);

  // ---- layer 2: K=64, C=128, relu ----
  { dim3 g((NN + 127)/128, 512/64);
    gemm_mfma<64,false><<<g, 256, 0, stream>>>(X0, W2t, H16, nullptr, NN, 512); }
  att_scores_w<128><<<NN/4, 256, 0, stream>>>(H16, a2s, a2d, AS, AD);
  agg128_k<true><<<NN/4, 256, 0, stream>>>(OFF, ESRC, AS, AD, H16, b2, X1);

  // ---- layer f: K=128, C=128, fused norm+residual output ----
  { dim3 g((NN + 127)/128, 512/64);
    gemm_mfma<128,false><<<g, 256, 0, stream>>>(X1, Wft, H16, nullptr, NN, 512); }
  att_scores_w<128><<<NN/4, 256, 0, stream>>>(H16, afs, afd, AS, AD);
  agg128_final_k<<<NN/4, 256, 0, stream>>>(OFF, ESRC, AS, AD, H16, bf, RES, bres, out);
}